// Round 1
// baseline (162.977 us; speedup 1.0000x reference)
//
#include <hip/hip_runtime.h>
#include <hip/hip_bf16.h>

#define B_ 2
#define H_ 4
#define T_ 2048
#define D_ 63
#define NS_ 21
#define DP_ 64

typedef __attribute__((ext_vector_type(4))) float f32x4;
typedef __attribute__((ext_vector_type(8))) short short8;
typedef __attribute__((ext_vector_type(4))) short short4_t;

static __device__ __forceinline__ short f2bf(float f) {
    union { float f; unsigned u; } c; c.f = f;
    unsigned r = c.u + 0x7FFFu + ((c.u >> 16) & 1u);
    return (short)(r >> 16);
}

// ---------------------------------------------------------------------------
// Prep: rotate q,k by quaternion Lie-algebra RoPE, cast to bf16 padded to 64;
// also write V transposed [bh][64][T] in bf16.
// One block per (b,t); quaternion computed once, shared over 4 heads.
// ---------------------------------------------------------------------------
__global__ __launch_bounds__(64) void geope_prep(
    const float* __restrict__ q, const float* __restrict__ kk,
    const float* __restrict__ v, const float* __restrict__ coords,
    short* __restrict__ qr, short* __restrict__ kr, short* __restrict__ vt)
{
    const int bt = blockIdx.x;
    const int b = bt / T_;
    const int t = bt - b * T_;
    const int tid = threadIdx.x;

    __shared__ float sw[NS_], sx[NS_], sy[NS_], sz[NS_];
    if (tid < NS_) {
        const float cx = coords[(size_t)(b*T_ + t)*3 + 0] * 1e-4f;
        const float cy = coords[(size_t)(b*T_ + t)*3 + 1] * 1e-4f;
        const float cz = coords[(size_t)(b*T_ + t)*3 + 2] * 1e-4f;
        const float invf = exp2f(-5.0f * (float)tid / 21.0f);  // 32^(-s/21)
        const float tx = cx*invf, ty = cy*invf, tz = cz*invf;
        const float Theta = (1.0f/3.0f)*sqrtf(tx*tx + ty*ty + tz*tz + 1e-8f);
        const float hf = 0.5f*Theta;
        const float s = sinf(hf)/(3.0f*Theta + 1e-8f);
        sw[tid] = cosf(hf);
        sx[tid] = s*tx; sy[tid] = s*ty; sz[tid] = s*tz;
    }
    __syncthreads();

    // 8 combos (4 heads x {q,k}) x 21 subvectors
    for (int task = tid; task < 8*NS_; task += 64) {
        const int s  = task % NS_;
        const int cb = task / NS_;
        const int h  = cb >> 1;
        const float* src = (cb & 1) ? kk : q;
        short* dst = (cb & 1) ? kr : qr;
        const size_t ib = ((size_t)((b*H_ + h)*T_) + t)*D_ + s*3;
        const float vx = src[ib+0], vy = src[ib+1], vz = src[ib+2];
        const float w = sw[s], qx = sx[s], qy = sy[s], qz = sz[s];
        const float t0 = qy*vz - qz*vy;
        const float t1 = qz*vx - qx*vz;
        const float t2 = qx*vy - qy*vx;
        const float px = vx + 2.0f*w*t0 + 2.0f*(qy*t2 - qz*t1);
        const float py = vy + 2.0f*w*t1 + 2.0f*(qz*t0 - qx*t2);
        const float pz = vz + 2.0f*w*t2 + 2.0f*(qx*t1 - qy*t0);
        const size_t ob = ((size_t)((b*H_ + h)*T_) + t)*DP_ + s*3;
        dst[ob+0] = f2bf(px); dst[ob+1] = f2bf(py); dst[ob+2] = f2bf(pz);
    }
    // zero-pad d=63 of q_rot/k_rot (must be 0 so scores are unaffected)
    if (tid < 8) {
        const int h = tid >> 1;
        short* dst = (tid & 1) ? kr : qr;
        dst[((size_t)((b*H_ + h)*T_) + t)*DP_ + 63] = 0;
    }
    // V transpose + bf16 cast: vt[bh][d][t]
    for (int i = tid; i < H_*DP_; i += 64) {
        const int h = i / DP_;
        const int d = i - h*DP_;
        const float val = (d < D_) ? v[((size_t)((b*H_ + h)*T_) + t)*D_ + d] : 0.0f;
        vt[((size_t)((b*H_ + h)*DP_) + d)*T_ + t] = f2bf(val);
    }
}

// ---------------------------------------------------------------------------
// Flash attention, bf16 MFMA 16x16x32, f32 accum.
// Block = 256 thr = 4 waves; each wave owns 16 q rows; KV tile = 64 keys.
// Swapped QK^T (mfma(K,Q) -> S^T) so softmax key-reduce is in-lane + 2 shfl.
// P staged via per-wave LDS (double-buffered) to reach MFMA A-layout.
// ---------------------------------------------------------------------------
__global__ __launch_bounds__(256) void geope_attn(
    const short* __restrict__ qr, const short* __restrict__ kr,
    const short* __restrict__ vt, float* __restrict__ out)
{
    constexpr int KVB = 64;
    const int nqb = T_ / 64;
    const int blk = blockIdx.x;
    const int bh = blk / nqb;
    const int q0 = (blk - bh*nqb) * 64;
    const int wave = threadIdx.x >> 6;
    const int lane = threadIdx.x & 63;
    const int r = lane & 15;   // low nibble: q column in S^T, d column in O
    const int g = lane >> 4;   // lane group
    const int qw = q0 + wave*16;

    const short* Qb = qr + (size_t)bh*T_*DP_;
    const short* Kb = kr + (size_t)bh*T_*DP_;
    const short* Vb = vt + (size_t)bh*DP_*T_;

    // Q fragments (held in regs across the KV loop): A/B-frag layout,
    // lane reads Q[qw + r][g*8 + 32*c .. +7]
    const short8 qf0 = *(const short8*)(Qb + (size_t)(qw + r)*DP_ + g*8);
    const short8 qf1 = *(const short8*)(Qb + (size_t)(qw + r)*DP_ + 32 + g*8);

    f32x4 oacc[4] = {};          // O[q=(g*4+j)][d=dt*16+r]
    float m = -INFINITY, l = 0.0f;

    __shared__ short p_lds[2][4][16][72];  // [buf][wave][q][key] (+pad to 144B rows)

    const float sscale = 0.18176249f;  // log2(e)/sqrt(63)

    int buf = 0;
    for (int k0 = 0; k0 < T_; k0 += KVB) {
        // ---- S^T = K_tile @ Q^T  (lane: key=k0+kt*16+g*4+j, q=qw+r) ----
        f32x4 st[4] = {};
        #pragma unroll
        for (int kt = 0; kt < 4; ++kt) {
            const short* kp = Kb + (size_t)(k0 + kt*16 + r)*DP_ + g*8;
            const short8 kf0 = *(const short8*)(kp);
            const short8 kf1 = *(const short8*)(kp + 32);
            st[kt] = __builtin_amdgcn_mfma_f32_16x16x32_bf16(kf0, qf0, st[kt], 0, 0, 0);
            st[kt] = __builtin_amdgcn_mfma_f32_16x16x32_bf16(kf1, qf1, st[kt], 0, 0, 0);
        }
        // ---- online softmax over the 64-key tile ----
        float tmax = st[0][0];
        #pragma unroll
        for (int kt = 0; kt < 4; ++kt)
            #pragma unroll
            for (int j = 0; j < 4; ++j) tmax = fmaxf(tmax, st[kt][j]);
        tmax = fmaxf(tmax, __shfl_xor(tmax, 16));
        tmax = fmaxf(tmax, __shfl_xor(tmax, 32));
        const float mnew = fmaxf(m, tmax * sscale);
        const float sf = exp2f(m - mnew);          // m=-inf first iter -> 0
        float psum = 0.0f;
        #pragma unroll
        for (int kt = 0; kt < 4; ++kt) {
            const float p0 = exp2f(st[kt][0]*sscale - mnew);
            const float p1 = exp2f(st[kt][1]*sscale - mnew);
            const float p2 = exp2f(st[kt][2]*sscale - mnew);
            const float p3 = exp2f(st[kt][3]*sscale - mnew);
            psum += (p0 + p1) + (p2 + p3);
            short4_t pk;
            pk[0] = f2bf(p0); pk[1] = f2bf(p1); pk[2] = f2bf(p2); pk[3] = f2bf(p3);
            *(short4_t*)&p_lds[buf][wave][r][kt*16 + g*4] = pk;   // p_lds[q][key]
        }
        psum += __shfl_xor(psum, 16);
        psum += __shfl_xor(psum, 32);
        l = l * sf + psum;
        m = mnew;
        // ---- rescale O (per-row scale lives in lane (g*4+j) of S^T layout) ----
        #pragma unroll
        for (int j = 0; j < 4; ++j) {
            const float sfr = __shfl(sf, g*4 + j);
            #pragma unroll
            for (int dt = 0; dt < 4; ++dt) oacc[dt][j] *= sfr;
        }
        __syncthreads();   // order LDS write -> cross-lane read (per-wave buffers)
        // ---- O += P @ V ----
        const short8 pa0 = *(const short8*)&p_lds[buf][wave][r][g*8];
        const short8 pa1 = *(const short8*)&p_lds[buf][wave][r][32 + g*8];
        #pragma unroll
        for (int dt = 0; dt < 4; ++dt) {
            const short* vp = Vb + (size_t)(dt*16 + r)*T_ + k0 + g*8;
            const short8 vf0 = *(const short8*)(vp);
            const short8 vf1 = *(const short8*)(vp + 32);
            oacc[dt] = __builtin_amdgcn_mfma_f32_16x16x32_bf16(pa0, vf0, oacc[dt], 0, 0, 0);
            oacc[dt] = __builtin_amdgcn_mfma_f32_16x16x32_bf16(pa1, vf1, oacc[dt], 0, 0, 0);
        }
        buf ^= 1;
    }

    // ---- epilogue: divide by l, store f32 (skip pad col d=63) ----
    #pragma unroll
    for (int j = 0; j < 4; ++j) {
        const float linv = 1.0f / __shfl(l, g*4 + j);
        float* orow = out + ((size_t)bh*T_ + (qw + g*4 + j))*D_;
        #pragma unroll
        for (int dt = 0; dt < 4; ++dt) {
            const int d = dt*16 + r;
            if (d < D_) orow[d] = oacc[dt][j] * linv;
        }
    }
}

extern "C" void kernel_launch(void* const* d_in, const int* in_sizes, int n_in,
                              void* d_out, int out_size, void* d_ws, size_t ws_size,
                              hipStream_t stream)
{
    const float* q      = (const float*)d_in[0];
    const float* k      = (const float*)d_in[1];
    const float* v      = (const float*)d_in[2];
    const float* coords = (const float*)d_in[3];
    float* out = (float*)d_out;

    short* qr = (short*)d_ws;
    short* kr = qr + (size_t)B_*H_*T_*DP_;
    short* vt = kr + (size_t)B_*H_*T_*DP_;

    geope_prep<<<dim3(B_*T_), dim3(64), 0, stream>>>(q, k, v, coords, qr, kr, vt);
    geope_attn<<<dim3(B_*H_*(T_/64)), dim3(256), 0, stream>>>(qr, kr, vt, out);
}

// Round 2
// 147.986 us; speedup vs baseline: 1.1013x; 1.1013x over previous
//
#include <hip/hip_runtime.h>
#include <hip/hip_bf16.h>

#define B_ 2
#define H_ 4
#define BH_ 8
#define T_ 2048
#define D_ 63
#define NS_ 21
#define DP_ 64
#define NSPLIT_ 4

typedef __attribute__((ext_vector_type(4))) float f32x4;
typedef __attribute__((ext_vector_type(2))) float f32x2;
typedef __attribute__((ext_vector_type(8))) short short8;
typedef __attribute__((ext_vector_type(4))) short short4_t;

// log2(e) / sqrt(63)  (folded into Q during prep)
#define SSCALE 0.18176249f

static __device__ __forceinline__ short f2bf(float f) {
    union { float f; unsigned u; } c; c.f = f;
    unsigned r = c.u + 0x7FFFu + ((c.u >> 16) & 1u);
    return (short)(r >> 16);
}

// ---------------------------------------------------------------------------
// Rotate q,k by quaternion Lie-algebra RoPE -> bf16, padded to 64, Q pre-scaled
// by log2(e)/sqrt(D). One block per (b,t); LDS-staged for coalesced IO.
// ---------------------------------------------------------------------------
__global__ __launch_bounds__(64) void geope_rotate(
    const float* __restrict__ q, const float* __restrict__ kk,
    const float* __restrict__ coords,
    short* __restrict__ qr, short* __restrict__ kr)
{
    const int bt = blockIdx.x;
    const int b = bt / T_;
    const int t = bt - b * T_;
    const int tid = threadIdx.x;

    __shared__ float sIn[8][64];          // 8 rows = 4 heads x {q,k}
    __shared__ float sw[NS_], sx[NS_], sy[NS_], sz[NS_];
    __shared__ short sOut[8][64];

    // coalesced load of the 8 source rows
    for (int idx = tid; idx < 8 * D_; idx += 64) {
        const int row = idx / D_;
        const int col = idx - row * D_;
        const int h = row >> 1;
        const float* src = (row & 1) ? kk : q;
        sIn[row][col] = src[((size_t)((b*H_ + h)*T_) + t)*D_ + col];
    }
    if (tid < NS_) {
        const float cx = coords[(size_t)(b*T_ + t)*3 + 0] * 1e-4f;
        const float cy = coords[(size_t)(b*T_ + t)*3 + 1] * 1e-4f;
        const float cz = coords[(size_t)(b*T_ + t)*3 + 2] * 1e-4f;
        const float invf = exp2f(-5.0f * (float)tid / 21.0f);  // 32^(-s/21)
        const float tx = cx*invf, ty = cy*invf, tz = cz*invf;
        const float Theta = (1.0f/3.0f)*sqrtf(tx*tx + ty*ty + tz*tz + 1e-8f);
        const float hf = 0.5f*Theta;
        const float s = sinf(hf)/(3.0f*Theta + 1e-8f);
        sw[tid] = cosf(hf);
        sx[tid] = s*tx; sy[tid] = s*ty; sz[tid] = s*tz;
    }
    if (tid < 8) sOut[tid][63] = 0;       // zero pad column
    __syncthreads();

    for (int task = tid; task < 8*NS_; task += 64) {
        const int row = task / NS_;
        const int s   = task - row*NS_;
        const float vx = sIn[row][s*3+0], vy = sIn[row][s*3+1], vz = sIn[row][s*3+2];
        const float w = sw[s], qx = sx[s], qy = sy[s], qz = sz[s];
        const float t0 = qy*vz - qz*vy;
        const float t1 = qz*vx - qx*vz;
        const float t2 = qx*vy - qy*vx;
        float px = vx + 2.0f*w*t0 + 2.0f*(qy*t2 - qz*t1);
        float py = vy + 2.0f*w*t1 + 2.0f*(qz*t0 - qx*t2);
        float pz = vz + 2.0f*w*t2 + 2.0f*(qx*t1 - qy*t0);
        const float mult = (row & 1) ? 1.0f : SSCALE;  // scale only Q
        sOut[row][s*3+0] = f2bf(px*mult);
        sOut[row][s*3+1] = f2bf(py*mult);
        sOut[row][s*3+2] = f2bf(pz*mult);
    }
    __syncthreads();

    // coalesced store: 8 rows x 64 shorts; each thread one short8
    {
        const int row = tid >> 3;
        const int off = (tid & 7) * 8;
        const int h = row >> 1;
        short* dst = (row & 1) ? kr : qr;
        *(short8*)(dst + ((size_t)((b*H_ + h)*T_) + t)*DP_ + off) = *(short8*)&sOut[row][off];
    }
}

// ---------------------------------------------------------------------------
// Tiled V transpose + bf16 cast: vt[bh][d(64)][t], coalesced both sides.
// ---------------------------------------------------------------------------
__global__ __launch_bounds__(256) void geope_vtrans(
    const float* __restrict__ v, short* __restrict__ vt)
{
    const int blk = blockIdx.x;          // bh*(T/64) + ttile
    const int bh = blk >> 5;
    const int t0 = (blk & 31) * 64;
    const int tid = threadIdx.x;
    __shared__ short tile[64][65];

    for (int idx = tid; idx < 64*64; idx += 256) {
        const int tt = idx >> 6;
        const int d  = idx & 63;
        const float val = (d < D_) ? v[((size_t)bh*T_ + t0 + tt)*D_ + d] : 0.0f;
        tile[tt][d] = f2bf(val);
    }
    __syncthreads();

    const int d  = tid >> 2;
    const int tq = (tid & 3) * 16;
    short8 o0, o1;
    #pragma unroll
    for (int i = 0; i < 8; ++i) o0[i] = tile[tq + i][d];
    #pragma unroll
    for (int i = 0; i < 8; ++i) o1[i] = tile[tq + 8 + i][d];
    short* dst = vt + ((size_t)bh*DP_ + d)*T_ + t0 + tq;
    *(short8*)(dst)     = o0;
    *(short8*)(dst + 8) = o1;
}

// ---------------------------------------------------------------------------
// Flash attention over a KV segment. bf16 MFMA 16x16x32, f32 accum.
// Block = 4 waves; wave owns 16 q rows. No per-iter barrier (P buffer is
// per-wave; in-wave LDS ordering via lgkmcnt). Q pre-scaled -> exp2 domain.
// NSPLIT>1: write unnormalized O + (m,l) partials. NSPLIT==1: final out.
// ---------------------------------------------------------------------------
template<int NSPLIT>
__global__ __launch_bounds__(256) void geope_attn_t(
    const short* __restrict__ qr, const short* __restrict__ kr,
    const short* __restrict__ vt, float* __restrict__ out,
    float* __restrict__ opart, float* __restrict__ ml)
{
    constexpr int SEG = T_ / NSPLIT;
    const int nqb = T_ / 64;
    const int blk = blockIdx.x;
    const int seg = blockIdx.y;
    const int bh = blk / nqb;
    const int q0 = (blk - bh*nqb) * 64;
    const int wave = threadIdx.x >> 6;
    const int lane = threadIdx.x & 63;
    const int r = lane & 15;
    const int g = lane >> 4;
    const int qw = q0 + wave*16;

    const short* Qb = qr + (size_t)bh*T_*DP_;
    const short* Kb = kr + (size_t)bh*T_*DP_;
    const short* Vb = vt + (size_t)bh*DP_*T_;

    const short8 qf0 = *(const short8*)(Qb + (size_t)(qw + r)*DP_ + g*8);
    const short8 qf1 = *(const short8*)(Qb + (size_t)(qw + r)*DP_ + 32 + g*8);

    f32x4 oacc[4] = {};
    float m = -INFINITY, l = 0.0f;

    __shared__ short p_lds[4][16][72];   // [wave][q][key]

    const int kbeg = seg * SEG;
    const int kend = kbeg + SEG;
    for (int k0 = kbeg; k0 < kend; k0 += 64) {
        // S^T = K_tile @ Q^T  (lane: key=k0+kt*16+g*4+j, q=qw+r), exp2 domain
        f32x4 st[4] = {};
        #pragma unroll
        for (int kt = 0; kt < 4; ++kt) {
            const short* kp = Kb + (size_t)(k0 + kt*16 + r)*DP_ + g*8;
            const short8 kf0 = *(const short8*)(kp);
            const short8 kf1 = *(const short8*)(kp + 32);
            st[kt] = __builtin_amdgcn_mfma_f32_16x16x32_bf16(kf0, qf0, st[kt], 0, 0, 0);
            st[kt] = __builtin_amdgcn_mfma_f32_16x16x32_bf16(kf1, qf1, st[kt], 0, 0, 0);
        }
        // online softmax
        float tmax = st[0][0];
        #pragma unroll
        for (int kt = 0; kt < 4; ++kt)
            #pragma unroll
            for (int j = 0; j < 4; ++j) tmax = fmaxf(tmax, st[kt][j]);
        tmax = fmaxf(tmax, __shfl_xor(tmax, 16));
        tmax = fmaxf(tmax, __shfl_xor(tmax, 32));
        const float mnew = fmaxf(m, tmax);
        const float sf = exp2f(m - mnew);
        float psum = 0.0f;
        #pragma unroll
        for (int kt = 0; kt < 4; ++kt) {
            const float p0 = exp2f(st[kt][0] - mnew);
            const float p1 = exp2f(st[kt][1] - mnew);
            const float p2 = exp2f(st[kt][2] - mnew);
            const float p3 = exp2f(st[kt][3] - mnew);
            psum += (p0 + p1) + (p2 + p3);
            short4_t pk;
            pk[0] = f2bf(p0); pk[1] = f2bf(p1); pk[2] = f2bf(p2); pk[3] = f2bf(p3);
            *(short4_t*)&p_lds[wave][r][kt*16 + g*4] = pk;
        }
        psum += __shfl_xor(psum, 16);
        psum += __shfl_xor(psum, 32);
        l = l * sf + psum;
        m = mnew;
        #pragma unroll
        for (int j = 0; j < 4; ++j) {
            const float sfr = __shfl(sf, g*4 + j);
            #pragma unroll
            for (int dt = 0; dt < 4; ++dt) oacc[dt][j] *= sfr;
        }
        // O += P @ V   (in-wave LDS RAW ordered by lgkmcnt; no barrier)
        const short8 pa0 = *(const short8*)&p_lds[wave][r][g*8];
        const short8 pa1 = *(const short8*)&p_lds[wave][r][32 + g*8];
        #pragma unroll
        for (int dt = 0; dt < 4; ++dt) {
            const short* vp = Vb + (size_t)(dt*16 + r)*T_ + k0 + g*8;
            const short8 vf0 = *(const short8*)(vp);
            const short8 vf1 = *(const short8*)(vp + 32);
            oacc[dt] = __builtin_amdgcn_mfma_f32_16x16x32_bf16(pa0, vf0, oacc[dt], 0, 0, 0);
            oacc[dt] = __builtin_amdgcn_mfma_f32_16x16x32_bf16(pa1, vf1, oacc[dt], 0, 0, 0);
        }
    }

    if constexpr (NSPLIT == 1) {
        #pragma unroll
        for (int j = 0; j < 4; ++j) {
            const float linv = 1.0f / __shfl(l, g*4 + j);
            float* orow = out + ((size_t)bh*T_ + (qw + g*4 + j))*D_;
            #pragma unroll
            for (int dt = 0; dt < 4; ++dt) {
                const int d = dt*16 + r;
                if (d < D_) orow[d] = oacc[dt][j] * linv;
            }
        }
    } else {
        float* op = opart + ((size_t)seg*BH_*T_ + (size_t)bh*T_)*DP_;
        #pragma unroll
        for (int j = 0; j < 4; ++j) {
            float* orow = op + (size_t)(qw + g*4 + j)*DP_;
            #pragma unroll
            for (int dt = 0; dt < 4; ++dt) orow[dt*16 + r] = oacc[dt][j];
        }
        if (g == 0) {
            f32x2 mlv; mlv[0] = m; mlv[1] = l;
            *(f32x2*)(ml + ((size_t)seg*BH_*T_ + (size_t)bh*T_ + qw + r)*2) = mlv;
        }
    }
}

// ---------------------------------------------------------------------------
// Combine KV-split partials: one wave per q-row.
// ---------------------------------------------------------------------------
__global__ __launch_bounds__(256) void geope_combine(
    const float* __restrict__ opart, const float* __restrict__ ml,
    float* __restrict__ out)
{
    const int row = blockIdx.x*4 + (threadIdx.x >> 6);
    const int d   = threadIdx.x & 63;
    float mv[NSPLIT_], lv[NSPLIT_];
    float M = -INFINITY;
    #pragma unroll
    for (int s = 0; s < NSPLIT_; ++s) {
        const f32x2 v = *(const f32x2*)(ml + ((size_t)s*BH_*T_ + row)*2);
        mv[s] = v[0]; lv[s] = v[1];
        M = fmaxf(M, mv[s]);
    }
    float L = 0.0f, o = 0.0f;
    #pragma unroll
    for (int s = 0; s < NSPLIT_; ++s) {
        const float w = exp2f(mv[s] - M);
        L += lv[s] * w;
        o += opart[((size_t)s*BH_*T_ + row)*DP_ + d] * w;
    }
    if (d < D_) out[(size_t)row*D_ + d] = o / L;
}

extern "C" void kernel_launch(void* const* d_in, const int* in_sizes, int n_in,
                              void* d_out, int out_size, void* d_ws, size_t ws_size,
                              hipStream_t stream)
{
    const float* q      = (const float*)d_in[0];
    const float* k      = (const float*)d_in[1];
    const float* v      = (const float*)d_in[2];
    const float* coords = (const float*)d_in[3];
    float* out = (float*)d_out;

    const size_t NQK = (size_t)B_*H_*T_*DP_;          // elements per bf16 buf
    short* qr = (short*)d_ws;
    short* kr = qr + NQK;
    short* vt = kr + NQK;
    float* opart = (float*)(vt + NQK);
    float* ml = opart + (size_t)NSPLIT_*BH_*T_*DP_;
    const size_t need = 3*NQK*sizeof(short)
                      + (size_t)NSPLIT_*BH_*T_*DP_*sizeof(float)
                      + (size_t)NSPLIT_*BH_*T_*2*sizeof(float);

    geope_rotate<<<dim3(B_*T_), dim3(64), 0, stream>>>(q, k, coords, qr, kr);
    geope_vtrans<<<dim3(BH_*32), dim3(256), 0, stream>>>(v, vt);

    if (ws_size >= need) {
        geope_attn_t<NSPLIT_><<<dim3(BH_*32, NSPLIT_), dim3(256), 0, stream>>>(
            qr, kr, vt, nullptr, opart, ml);
        geope_combine<<<dim3(BH_*T_/4), dim3(256), 0, stream>>>(opart, ml, out);
    } else {
        geope_attn_t<1><<<dim3(BH_*32, 1), dim3(256), 0, stream>>>(
            qr, kr, vt, out, nullptr, nullptr);
    }
}